// Round 8
// baseline (85.881 us; speedup 1.0000x reference)
//
#include <hip/hip_runtime.h>

// DirectionalScan: B=4, H=64, W=64, D=512, N=8
// out = ((scan_h(x) + scan_v(x)) @ Wp^T) + b_proj
#define BB 4
#define HH 64
#define WW 64
#define DD 512
#define NS 8
#define MROWS (BB * HH * WW)  // 16384

typedef __attribute__((ext_vector_type(8))) __bf16 bf16x8;
typedef __attribute__((ext_vector_type(4))) float f32x4;

__device__ inline short f2bf(float f) {  // RNE f32 -> bf16 bits
  unsigned u = __float_as_uint(f);
  return (short)((u + 0x7fff + ((u >> 16) & 1)) >> 16);
}
__device__ inline float bf2f(short s) {
  return __uint_as_float(((unsigned)(unsigned short)s) << 16);
}

// one SSM step: update states s[], return C.s + D*x via 3-level tree
__device__ inline float ssm_step(float xv, float* s, const float* a,
                                 const float* bm, const float* cm, float dk) {
#pragma unroll
  for (int n = 0; n < NS; ++n) s[n] = fmaf(a[n], s[n], bm[n] * xv);
  float p0 = s[0] * cm[0], p1 = s[1] * cm[1], p2 = s[2] * cm[2],
        p3 = s[3] * cm[3], p4 = s[4] * cm[4], p5 = s[5] * cm[5],
        p6 = s[6] * cm[6], p7 = s[7] * cm[7];
  float q0 = p0 + p1, q1 = p2 + p3, q2 = p4 + p5, q3 = p6 + p7;
  return fmaf(dk, xv, (q0 + q1) + (q2 + q3));
}

// ---------------- kernel 1: scan_h (writes y_h bf16) + fused Wp->bf16 -------
__global__ __launch_bounds__(256) void scan_h_kernel(
    const float* __restrict__ x, const float* __restrict__ A,
    const float* __restrict__ Bm, const float* __restrict__ Cm,
    const float* __restrict__ Dsk, short* __restrict__ y,
    const float* __restrict__ Wp, short* __restrict__ wb) {
  if (blockIdx.x >= 256) {
    const int cid = (blockIdx.x - 256) * 2 + blockIdx.y;  // 0..127
    const int i = (cid * 256 + (int)threadIdx.x) * 8;
    const float4 v0 = *(const float4*)&Wp[i];
    const float4 v1 = *(const float4*)&Wp[i + 4];
    short r[8];
    r[0] = f2bf(v0.x); r[1] = f2bf(v0.y); r[2] = f2bf(v0.z); r[3] = f2bf(v0.w);
    r[4] = f2bf(v1.x); r[5] = f2bf(v1.y); r[6] = f2bf(v1.z); r[7] = f2bf(v1.w);
    *(short4*)&wb[i] = *(short4*)&r[0];
    *(short4*)&wb[i + 4] = *(short4*)&r[4];
    return;
  }

  const int seq = blockIdx.x;  // 0..255 = b*64 + w
  const int d = blockIdx.y * 256 + threadIdx.x;
  const int b = seq >> 6;
  const int r = seq & 63;

  size_t base = ((size_t)b * HH * WW + r) * DD + d;
  const size_t step = (size_t)WW * DD;

  float a[NS], bm[NS], cm[NS], s[NS];
#pragma unroll
  for (int i = 0; i < NS; i += 4) {
    float4 t;
    t = *(const float4*)&A[(size_t)d * NS + i];
    a[i] = t.x; a[i + 1] = t.y; a[i + 2] = t.z; a[i + 3] = t.w;
    t = *(const float4*)&Bm[(size_t)d * NS + i];
    bm[i] = t.x; bm[i + 1] = t.y; bm[i + 2] = t.z; bm[i + 3] = t.w;
    t = *(const float4*)&Cm[(size_t)d * NS + i];
    cm[i] = t.x; cm[i + 1] = t.y; cm[i + 2] = t.z; cm[i + 3] = t.w;
  }
  const float dk = Dsk[d];
#pragma unroll
  for (int i = 0; i < NS; ++i) s[i] = 0.f;

  // 2-chunk-ahead prefetch (4-slot ring, unroll 4 keeps indices static)
  float xs[4][8];
#pragma unroll
  for (int i = 0; i < 8; ++i) xs[0][i] = x[base + (size_t)i * step];
#pragma unroll
  for (int i = 0; i < 8; ++i) xs[1][i] = x[base + (size_t)(8 + i) * step];

#pragma unroll 4
  for (int c = 0; c < 8; ++c) {
    const int cur = c & 3;
    if (c < 6) {
      const size_t pbase = base + 16 * step;
#pragma unroll
      for (int i = 0; i < 8; ++i)
        xs[(c + 2) & 3][i] = x[pbase + (size_t)i * step];
    }
#pragma unroll
    for (int i = 0; i < 8; ++i)
      y[base + (size_t)i * step] = f2bf(ssm_step(xs[cur][i], s, a, bm, cm, dk));
    base += 8 * step;
  }
}

// ------- kernel 2: pipelined scan_v + y_h add + GEMM + bias ----------------
// One block per (b,h) = 64 contiguous output rows; 512 threads = 8 waves.
// 4 pipeline stages m=0..3: {scan w-chunks 2m,2m+1 -> Ys rows 16m..16m+15}
// -> barrier -> {MFMA K-sweep for m-frag m, epilogue store}. Scan prefetch
// for the NEXT stage flies under this stage's MFMA sweep. B-fragments read
// directly from L2 (Wp bf16 = 512 KB, L2-resident) — no Bs LDS, no staging.
__global__ __launch_bounds__(512) void scanv_gemm_kernel(
    const float* __restrict__ x, const float* __restrict__ A,
    const float* __restrict__ Bm, const float* __restrict__ Cm,
    const float* __restrict__ Dsk, const short* __restrict__ yh,
    const short* __restrict__ Wb, const float* __restrict__ bias,
    float* __restrict__ out) {
  __shared__ __align__(16) short Ys[64 * DD];  // 64 KB [w][d^((w&7)<<3)]

  const int tid = (int)threadIdx.x;  // 0..511
  const int lane = tid & 63;
  const int wid = tid >> 6;  // 0..7
  const int m0 = blockIdx.x * 64;
  const int d = tid;

  float a[NS], bm[NS], cm[NS], s[NS];
#pragma unroll
  for (int i = 0; i < NS; i += 4) {
    float4 t;
    t = *(const float4*)&A[(size_t)d * NS + i];
    a[i] = t.x; a[i + 1] = t.y; a[i + 2] = t.z; a[i + 3] = t.w;
    t = *(const float4*)&Bm[(size_t)d * NS + i];
    bm[i] = t.x; bm[i + 1] = t.y; bm[i + 2] = t.z; bm[i + 3] = t.w;
    t = *(const float4*)&Cm[(size_t)d * NS + i];
    cm[i] = t.x; cm[i + 1] = t.y; cm[i + 2] = t.z; cm[i + 3] = t.w;
  }
  const float dk = Dsk[d];
#pragma unroll
  for (int i = 0; i < NS; ++i) s[i] = 0.f;

  const int fr = lane & 15;
  const int kfr = (lane >> 4) * 8;  // 0,8,16,24
  const int c16 = lane & 15;
  const int r4 = (lane >> 4) * 4;

  // bias for this wave's 4 n-frag columns (hoisted)
  float bv[4];
#pragma unroll
  for (int n = 0; n < 4; ++n) bv[n] = bias[wid * 64 + n * 16 + c16];

  size_t base = (size_t)m0 * DD + d;

  // 2-chunk-ahead prefetch ring (4 slots; all indices compile-time)
  float xs[4][8], yp[4][8];
#pragma unroll
  for (int i = 0; i < 8; ++i) xs[0][i] = x[base + (size_t)i * DD];
#pragma unroll
  for (int i = 0; i < 8; ++i) yp[0][i] = bf2f(yh[base + (size_t)i * DD]);
#pragma unroll
  for (int i = 0; i < 8; ++i) xs[1][i] = x[base + (size_t)(8 + i) * DD];
#pragma unroll
  for (int i = 0; i < 8; ++i) yp[1][i] = bf2f(yh[base + (size_t)(8 + i) * DD]);

#pragma unroll
  for (int m = 0; m < 4; ++m) {
    // ---- stage m scan: chunks 2m, 2m+1 -> Ys rows 16m..16m+15 ----
#pragma unroll
    for (int cc = 0; cc < 2; ++cc) {
      const int c = 2 * m + cc;
      const int cur = c & 3;
      if (c < 6) {  // prefetch chunk c+2 (consumed next stage, flies
                    // under this stage's MFMA sweep)
        const size_t pbase = base + 16 * DD;
#pragma unroll
        for (int i = 0; i < 8; ++i)
          xs[(c + 2) & 3][i] = x[pbase + (size_t)i * DD];
#pragma unroll
        for (int i = 0; i < 8; ++i)
          yp[(c + 2) & 3][i] = bf2f(yh[pbase + (size_t)i * DD]);
      }
#pragma unroll
      for (int i = 0; i < 8; ++i) {
        const int w = c * 8 + i;
        const float acc = ssm_step(xs[cur][i], s, a, bm, cm, dk) + yp[cur][i];
        Ys[w * DD + (d ^ ((w & 7) << 3))] = f2bf(acc);
      }
      base += 8 * DD;
    }

    __syncthreads();  // rows 16m..16m+15 visible to all waves.
    // (No barrier after the sweep: sweep m reads rows <=16m+15, stage m+1
    //  writes rows >=16m+16 — disjoint.)

    // ---- stage m GEMM: m-frag m over full K, then store ----
    f32x4 acc4[4];
#pragma unroll
    for (int n = 0; n < 4; ++n) acc4[n] = (f32x4){0.f, 0.f, 0.f, 0.f};

    const int r = m * 16 + fr;  // Ys row for the A-fragment
#pragma unroll 2
    for (int ks = 0; ks < 16; ++ks) {  // K-steps of 32, barrier-free
      const int kg = ks * 32 + kfr;
      const bf16x8 af =
          *(const bf16x8*)(const void*)&Ys[r * DD + (kg ^ ((r & 7) << 3))];
      bf16x8 bfv[4];
#pragma unroll
      for (int n = 0; n < 4; ++n) {
        const int nn = wid * 64 + n * 16 + fr;  // Wp row (out col)
        bfv[n] = *(const bf16x8*)(const void*)&Wb[(size_t)nn * DD + kg];
      }
#pragma unroll
      for (int n = 0; n < 4; ++n)
        acc4[n] =
            __builtin_amdgcn_mfma_f32_16x16x32_bf16(af, bfv[n], acc4[n], 0, 0, 0);
    }

    // epilogue for rows 16m..16m+15 (D layout: col=lane&15, row=(lane>>4)*4+j)
    const int rowb = m0 + m * 16 + r4;
#pragma unroll
    for (int n = 0; n < 4; ++n) {
      const int col = wid * 64 + n * 16 + c16;
#pragma unroll
      for (int j = 0; j < 4; ++j)
        out[(size_t)(rowb + j) * DD + col] = acc4[n][j] + bv[n];
    }
  }
}

// ---------------- launcher ----------------
extern "C" void kernel_launch(void* const* d_in, const int* in_sizes, int n_in,
                              void* d_out, int out_size, void* d_ws,
                              size_t ws_size, hipStream_t stream) {
  const float* x = (const float*)d_in[0];
  const float* A = (const float*)d_in[3];
  const float* Bm = (const float*)d_in[4];
  const float* Cm = (const float*)d_in[5];
  const float* Dsk = (const float*)d_in[6];
  const float* Wp = (const float*)d_in[7];
  const float* bpj = (const float*)d_in[8];
  float* out = (float*)d_out;

  short* yh = (short*)d_ws;                                    // 16 MB bf16 y_h
  short* wb = (short*)((char*)d_ws + (size_t)MROWS * DD * 2);  // 512 KB bf16 Wp

  const dim3 grid_h(256 + 64, DD / 256);
  scan_h_kernel<<<grid_h, 256, 0, stream>>>(x, A, Bm, Cm, Dsk, yh, Wp, wb);

  scanv_gemm_kernel<<<BB * HH, 512, 0, stream>>>(x, A, Bm, Cm, Dsk, yh, wb,
                                                 bpj, out);
}

// Round 9
// 77.411 us; speedup vs baseline: 1.1094x; 1.1094x over previous
//
#include <hip/hip_runtime.h>

// DirectionalScan: B=4, H=64, W=64, D=512, N=8
// out = ((scan_h(x) + scan_v(x)) @ Wp^T) + b_proj
// scan_h is computed as 4 parallel 16-step chunk-scans + carry fix-up applied
// at consumption time in kernel 2.
#define BB 4
#define HH 64
#define WW 64
#define DD 512
#define NS 8
#define MROWS (BB * HH * WW)  // 16384
#define CL 16                 // h-chunk length
#define NCH 4                 // chunks per h-sequence

typedef __attribute__((ext_vector_type(8))) __bf16 bf16x8;
typedef __attribute__((ext_vector_type(4))) float f32x4;

__device__ inline short f2bf(float f) {  // RNE f32 -> bf16 bits
  unsigned u = __float_as_uint(f);
  return (short)((u + 0x7fff + ((u >> 16) & 1)) >> 16);
}
__device__ inline float bf2f(short s) {
  return __uint_as_float(((unsigned)(unsigned short)s) << 16);
}
__device__ inline float bflo(unsigned u) {  // low short of a uint as bf16
  return __uint_as_float(u << 16);
}
__device__ inline float bfhi(unsigned u) {  // high short
  return __uint_as_float(u & 0xffff0000u);
}

// one SSM step: update states s[], return C.s + D*x via 3-level tree
__device__ inline float ssm_step(float xv, float* s, const float* a,
                                 const float* bm, const float* cm, float dk) {
#pragma unroll
  for (int n = 0; n < NS; ++n) s[n] = fmaf(a[n], s[n], bm[n] * xv);
  float p0 = s[0] * cm[0], p1 = s[1] * cm[1], p2 = s[2] * cm[2],
        p3 = s[3] * cm[3], p4 = s[4] * cm[4], p5 = s[5] * cm[5],
        p6 = s[6] * cm[6], p7 = s[7] * cm[7];
  float q0 = p0 + p1, q1 = p2 + p3, q2 = p4 + p5, q3 = p6 + p7;
  return fmaf(dk, xv, (q0 + q1) + (q2 + q3));
}

// ---------------- K1: chunked h-scan (local scans) + Wp->bf16 ---------------
// bx < 1024: block = (seq = b*64+w, ch). 512 thr = all channels d.
//   16-step local scan from s=0 over h in [16ch,16ch+16); writes local yh,
//   and (ch<3) the bf16 carry state c16[seq][ch][d][8].
// bx >= 1024: 64 blocks convert Wp f32 -> bf16 (8 elems/thread).
__global__ __launch_bounds__(512, 6) void scan_h_chunked(
    const float* __restrict__ x, const float* __restrict__ A,
    const float* __restrict__ Bm, const float* __restrict__ Cm,
    const float* __restrict__ Dsk, short* __restrict__ yh,
    short* __restrict__ c16, const float* __restrict__ Wp,
    short* __restrict__ wb) {
  const int bx = (int)blockIdx.x;
  const int tid = (int)threadIdx.x;
  if (bx >= 1024) {
    const int i = ((bx - 1024) * 512 + tid) * 8;
    const float4 v0 = *(const float4*)&Wp[i];
    const float4 v1 = *(const float4*)&Wp[i + 4];
    short r[8];
    r[0] = f2bf(v0.x); r[1] = f2bf(v0.y); r[2] = f2bf(v0.z); r[3] = f2bf(v0.w);
    r[4] = f2bf(v1.x); r[5] = f2bf(v1.y); r[6] = f2bf(v1.z); r[7] = f2bf(v1.w);
    *(short4*)&wb[i] = *(short4*)&r[0];
    *(short4*)&wb[i + 4] = *(short4*)&r[4];
    return;
  }

  const int seq = bx >> 2;  // 0..255 = b*64 + w
  const int ch = bx & 3;
  const int b = seq >> 6;
  const int w = seq & 63;
  const int d = tid;

  float a[NS], bm[NS], cm[NS], s[NS];
#pragma unroll
  for (int i = 0; i < NS; i += 4) {
    float4 t;
    t = *(const float4*)&A[(size_t)d * NS + i];
    a[i] = t.x; a[i + 1] = t.y; a[i + 2] = t.z; a[i + 3] = t.w;
    t = *(const float4*)&Bm[(size_t)d * NS + i];
    bm[i] = t.x; bm[i + 1] = t.y; bm[i + 2] = t.z; bm[i + 3] = t.w;
    t = *(const float4*)&Cm[(size_t)d * NS + i];
    cm[i] = t.x; cm[i + 1] = t.y; cm[i + 2] = t.z; cm[i + 3] = t.w;
  }
  const float dk = Dsk[d];
#pragma unroll
  for (int i = 0; i < NS; ++i) s[i] = 0.f;

  const size_t step = (size_t)WW * DD;
  size_t base = ((size_t)b * HH * WW + (size_t)(ch * CL) * WW + w) * DD + d;

  // all 16 x-loads issued up front (latency paid once, hidden by occupancy)
  float xv[CL];
#pragma unroll
  for (int i = 0; i < CL; ++i) xv[i] = x[base + (size_t)i * step];

#pragma unroll
  for (int i = 0; i < CL; ++i)
    yh[base + (size_t)i * step] = f2bf(ssm_step(xv[i], s, a, bm, cm, dk));

  if (ch < 3) {  // carry for downstream chunks
    short r[8];
#pragma unroll
    for (int n = 0; n < NS; ++n) r[n] = f2bf(s[n]);
    const size_t cb = (((size_t)seq * 3 + ch) * DD + d) * 8;
    *(short4*)&c16[cb] = *(short4*)&r[0];
    *(short4*)&c16[cb + 4] = *(short4*)&r[4];
  }
}

// ---------------- K1b: combine carries -> entry states E1..E3 --------------
// E_j (entry state of chunk j, j=1..3) = c_{j-1} + A^16 * E_{j-1},  E_0 = 0.
// block = seq (256), thread = d (512). ~100 ops + 96B traffic per thread.
__global__ __launch_bounds__(512) void combine_carries(
    const float* __restrict__ A, const short* __restrict__ c16,
    short* __restrict__ E) {
  const int seq = (int)blockIdx.x;
  const int d = (int)threadIdx.x;

  float a[NS];
  const float4 t0 = *(const float4*)&A[(size_t)d * NS];
  const float4 t1 = *(const float4*)&A[(size_t)d * NS + 4];
  a[0] = t0.x; a[1] = t0.y; a[2] = t0.z; a[3] = t0.w;
  a[4] = t1.x; a[5] = t1.y; a[6] = t1.z; a[7] = t1.w;
  float p16[NS];
#pragma unroll
  for (int n = 0; n < NS; ++n) p16[n] = a[n];
#pragma unroll
  for (int q = 0; q < 4; ++q)
#pragma unroll
    for (int n = 0; n < NS; ++n) p16[n] *= p16[n];  // a^16

  const size_t rb = ((size_t)seq * 3) * DD * 8 + (size_t)d * 8;
  float e[NS];
#pragma unroll
  for (int n = 0; n < NS; ++n) e[n] = 0.f;
#pragma unroll
  for (int j = 0; j < 3; ++j) {
    const uint4 u = *(const uint4*)&c16[rb + (size_t)j * DD * 8];
    float c[NS];
    c[0] = bflo(u.x); c[1] = bfhi(u.x); c[2] = bflo(u.y); c[3] = bfhi(u.y);
    c[4] = bflo(u.z); c[5] = bfhi(u.z); c[6] = bflo(u.w); c[7] = bfhi(u.w);
#pragma unroll
    for (int n = 0; n < NS; ++n) e[n] = fmaf(p16[n], e[n], c[n]);
    short r[8];
#pragma unroll
    for (int n = 0; n < NS; ++n) r[n] = f2bf(e[n]);
    *(short4*)&E[rb + (size_t)j * DD * 8] = *(short4*)&r[0];
    *(short4*)&E[rb + (size_t)j * DD * 8 + 4] = *(short4*)&r[4];
  }
}

// ------- K2: pipelined scan_v + corrected y_h add + GEMM + bias ------------
// R6 structure (42.2us baseline): one block per (b,h), 512 thr = 8 waves.
// Scan phase writes Ys (swizzled LDS); GEMM with wave-private Bs staging,
// counted vmcnt, barrier-free K-loop. NEW: yh values are chunk-local; the
// true value is yh_local + sum_n cm[n]*a[n]^(tl+1)*E[b,w,ch-1][d][n], with
// tl = h&15 and ch = h>>4 uniform per block -> coef[] per-thread constant.
__global__ __launch_bounds__(512) void scanv_gemm_kernel(
    const float* __restrict__ x, const float* __restrict__ A,
    const float* __restrict__ Bm, const float* __restrict__ Cm,
    const float* __restrict__ Dsk, const short* __restrict__ yh,
    const short* __restrict__ E, const short* __restrict__ Wb,
    const float* __restrict__ bias, float* __restrict__ out) {
  __shared__ __align__(16) short Ys[64 * DD];     // 64 KB [w][d^((w&7)<<3)]
  __shared__ __align__(16) short Bs[2][DD * 32];  // 2x32KB [n][k^((n&3)<<3)]

  const int tid = (int)threadIdx.x;  // 0..511
  const int lane = tid & 63;
  const int wid = tid >> 6;  // 0..7
  const int m0 = blockIdx.x * 64;
  const int d = tid;
  const int b = (int)blockIdx.x >> 6;
  const int h = (int)blockIdx.x & 63;
  const int ch = h >> 4;   // h-chunk of this row
  const int tl = h & 15;   // position within chunk

  auto stageB = [&](int ks, int buf) {
    const int k0 = ks * 32;
#pragma unroll
    for (int c = 0; c < 4; ++c) {
      const int chunk = wid * 4 + c;           // 0..31, 16 rows each
      const int n = chunk * 16 + (lane >> 2);  // Wp row
      const int kslot = ((lane & 3) ^ (n & 3)) << 3;
      const short* g = &Wb[(size_t)n * DD + k0 + kslot];
      __builtin_amdgcn_global_load_lds(
          (const __attribute__((address_space(1))) unsigned int*)g,
          (__attribute__((address_space(3))) unsigned int*)((char*)&Bs[buf][0] +
                                                            chunk * 1024),
          16, 0, 0);
    }
  };

  float a[NS], bm[NS], cm[NS], s[NS];
#pragma unroll
  for (int i = 0; i < NS; i += 4) {
    float4 t;
    t = *(const float4*)&A[(size_t)d * NS + i];
    a[i] = t.x; a[i + 1] = t.y; a[i + 2] = t.z; a[i + 3] = t.w;
    t = *(const float4*)&Bm[(size_t)d * NS + i];
    bm[i] = t.x; bm[i + 1] = t.y; bm[i + 2] = t.z; bm[i + 3] = t.w;
    t = *(const float4*)&Cm[(size_t)d * NS + i];
    cm[i] = t.x; cm[i + 1] = t.y; cm[i + 2] = t.z; cm[i + 3] = t.w;
  }
  const float dk = Dsk[d];
#pragma unroll
  for (int i = 0; i < NS; ++i) s[i] = 0.f;

  // correction coefficients: cm[n] * a[n]^(tl+1)  (uniform tl -> cheap)
  float coef[NS];
  {
    float ap[NS];
#pragma unroll
    for (int n = 0; n < NS; ++n) ap[n] = a[n];
    for (int t = 0; t < tl; ++t)
#pragma unroll
      for (int n = 0; n < NS; ++n) ap[n] *= a[n];
#pragma unroll
    for (int n = 0; n < NS; ++n) coef[n] = cm[n] * ap[n];
  }
  // E row base for this (b, ch-1, d); stride in w is 3*DD*8 bf16 elems
  const size_t e0 =
      (ch > 0) ? (((size_t)(b * 64) * 3 + (ch - 1)) * DD + d) * 8 : 0;

  // corrected y_h load: local value + C . (A^(tl+1) * entry_state)
  auto ld_yp = [&](size_t ybase, int w) -> float {
    float v = bf2f(yh[ybase]);
    if (ch > 0) {
      const uint4 eu = *(const uint4*)&E[e0 + (size_t)w * (3 * DD * 8)];
      float t0 = fmaf(coef[0], bflo(eu.x), coef[1] * bfhi(eu.x));
      float t1 = fmaf(coef[2], bflo(eu.y), coef[3] * bfhi(eu.y));
      float t2 = fmaf(coef[4], bflo(eu.z), coef[5] * bfhi(eu.z));
      float t3 = fmaf(coef[6], bflo(eu.w), coef[7] * bfhi(eu.w));
      v += (t0 + t1) + (t2 + t3);
    }
    return v;
  };

  size_t base = (size_t)m0 * DD + d;
  stageB(0, 0);  // lands under the scan; long done before GEMM

  // 2-chunk-ahead prefetch of x and corrected y_h
  float xs[4][8], yp[4][8];
#pragma unroll
  for (int i = 0; i < 8; ++i) xs[0][i] = x[base + (size_t)i * DD];
#pragma unroll
  for (int i = 0; i < 8; ++i) yp[0][i] = ld_yp(base + (size_t)i * DD, i);
#pragma unroll
  for (int i = 0; i < 8; ++i) xs[1][i] = x[base + (size_t)(8 + i) * DD];
#pragma unroll
  for (int i = 0; i < 8; ++i)
    yp[1][i] = ld_yp(base + (size_t)(8 + i) * DD, 8 + i);

#pragma unroll 4
  for (int c = 0; c < 8; ++c) {
    const int cur = c & 3;
    if (c < 6) {
      const size_t pbase = base + 16 * DD;
#pragma unroll
      for (int i = 0; i < 8; ++i)
        xs[(c + 2) & 3][i] = x[pbase + (size_t)i * DD];
#pragma unroll
      for (int i = 0; i < 8; ++i)
        yp[(c + 2) & 3][i] = ld_yp(pbase + (size_t)i * DD, (c + 2) * 8 + i);
    }
#pragma unroll
    for (int i = 0; i < 8; ++i) {
      const int w = c * 8 + i;
      const float acc = ssm_step(xs[cur][i], s, a, bm, cm, dk) + yp[cur][i];
      Ys[w * DD + (d ^ ((w & 7) << 3))] = f2bf(acc);
    }
    base += 8 * DD;
  }

  __syncthreads();  // Ys complete (only barrier in the kernel)

  // ---- GEMM: out[m0..+63][0..511] = Ys @ Wb^T + bias ----
  f32x4 acc4[4][4];
#pragma unroll
  for (int m = 0; m < 4; ++m)
#pragma unroll
    for (int n = 0; n < 4; ++n) acc4[m][n] = (f32x4){0.f, 0.f, 0.f, 0.f};

  const int fr = lane & 15;
  const int kfr = (lane >> 4) * 8;  // 0,8,16,24

  int cur = 0;
  for (int ks = 0; ks < 16; ++ks) {  // K-steps of 32, double-buffered
    if (ks < 15) {
      stageB(ks + 1, cur ^ 1);
      asm volatile("s_waitcnt vmcnt(4)" ::: "memory");  // stage(ks) done
    } else {
      asm volatile("s_waitcnt vmcnt(0)" ::: "memory");
    }
    __builtin_amdgcn_sched_barrier(0);  // rule #18: fence ds_reads below wait

    bf16x8 af[4], bfv[4];
    const int kg = ks * 32 + kfr;
#pragma unroll
    for (int m = 0; m < 4; ++m) {
      const int r = m * 16 + fr;  // Y row 0..63
      af[m] = *(const bf16x8*)(const void*)&Ys[r * DD + (kg ^ ((r & 7) << 3))];
    }
#pragma unroll
    for (int n = 0; n < 4; ++n) {
      const int nn = wid * 64 + n * 16 + fr;  // out col (wave-private rows)
      bfv[n] = *(const bf16x8*)(const void*)&Bs[cur][nn * 32 +
                                                     (kfr ^ ((nn & 3) << 3))];
    }
#pragma unroll
    for (int m = 0; m < 4; ++m)
#pragma unroll
      for (int n = 0; n < 4; ++n)
        acc4[m][n] = __builtin_amdgcn_mfma_f32_16x16x32_bf16(
            af[m], bfv[n], acc4[m][n], 0, 0, 0);
    __builtin_amdgcn_sched_barrier(0);  // keep iter body intact (WAR safety)
    cur ^= 1;
  }

  // epilogue: D layout col=lane&15, row=(lane>>4)*4+j  [m89 verified]
  const int c16l = lane & 15;
  const int r4 = (lane >> 4) * 4;
#pragma unroll
  for (int m = 0; m < 4; ++m) {
    const int rowb = m0 + m * 16 + r4;
#pragma unroll
    for (int n = 0; n < 4; ++n) {
      const int col = wid * 64 + n * 16 + c16l;
      const float bv = bias[col];
#pragma unroll
      for (int j = 0; j < 4; ++j)
        out[(size_t)(rowb + j) * DD + col] = acc4[m][n][j] + bv;
    }
  }
}

// ---------------- launcher ----------------
extern "C" void kernel_launch(void* const* d_in, const int* in_sizes, int n_in,
                              void* d_out, int out_size, void* d_ws,
                              size_t ws_size, hipStream_t stream) {
  const float* x = (const float*)d_in[0];
  const float* A = (const float*)d_in[3];
  const float* Bm = (const float*)d_in[4];
  const float* Cm = (const float*)d_in[5];
  const float* Dsk = (const float*)d_in[6];
  const float* Wp = (const float*)d_in[7];
  const float* bpj = (const float*)d_in[8];
  float* out = (float*)d_out;

  char* ws = (char*)d_ws;
  short* yh = (short*)ws;                               // 16 MB bf16 y_h local
  short* wb = (short*)(ws + 16u * 1024 * 1024);         // 512 KB bf16 Wp
  short* c16 = (short*)(ws + 17u * 1024 * 1024);        // 6 MB bf16 carries
  short* E = (short*)(ws + 24u * 1024 * 1024);          // 6 MB bf16 entries

  // K1: 1024 chunk-scan blocks + 64 conv blocks
  scan_h_chunked<<<1024 + 64, 512, 0, stream>>>(x, A, Bm, Cm, Dsk, yh, c16,
                                                Wp, wb);
  // K1b: carry combine (256 blocks)
  combine_carries<<<256, 512, 0, stream>>>(A, c16, E);
  // K2: fused v-scan + corrected add + GEMM
  scanv_gemm_kernel<<<BB * HH, 512, 0, stream>>>(x, A, Bm, Cm, Dsk, yh, E, wb,
                                                 bpj, out);
}

// Round 10
// 52.605 us; speedup vs baseline: 1.6326x; 1.4715x over previous
//
#include <hip/hip_runtime.h>

// DirectionalScan: B=4, H=64, W=64, D=512, N=8
// out = ((scan_h(x) + scan_v(x)) @ Wp^T) + b_proj
#define BB 4
#define HH 64
#define WW 64
#define DD 512
#define NS 8
#define MROWS (BB * HH * WW)  // 16384

typedef __attribute__((ext_vector_type(8))) __bf16 bf16x8;
typedef __attribute__((ext_vector_type(4))) float f32x4;

__device__ inline short f2bf(float f) {  // RNE f32 -> bf16 bits
  unsigned u = __float_as_uint(f);
  return (short)((u + 0x7fff + ((u >> 16) & 1)) >> 16);
}
__device__ inline float bf2f(short s) {
  return __uint_as_float(((unsigned)(unsigned short)s) << 16);
}

// one SSM step: update states s[], return C.s + D*x via 3-level tree
__device__ inline float ssm_step(float xv, float* s, const float* a,
                                 const float* bm, const float* cm, float dk) {
#pragma unroll
  for (int n = 0; n < NS; ++n) s[n] = fmaf(a[n], s[n], bm[n] * xv);
  float p0 = s[0] * cm[0], p1 = s[1] * cm[1], p2 = s[2] * cm[2],
        p3 = s[3] * cm[3], p4 = s[4] * cm[4], p5 = s[5] * cm[5],
        p6 = s[6] * cm[6], p7 = s[7] * cm[7];
  float q0 = p0 + p1, q1 = p2 + p3, q2 = p4 + p5, q3 = p6 + p7;
  return fmaf(dk, xv, (q0 + q1) + (q2 + q3));
}

// ---------------- kernel 1: scan_h (writes y_h bf16) + fused Wp->bf16 -------
// R6 version (proven ~10us, near its BW floor).
__global__ __launch_bounds__(256) void scan_h_kernel(
    const float* __restrict__ x, const float* __restrict__ A,
    const float* __restrict__ Bm, const float* __restrict__ Cm,
    const float* __restrict__ Dsk, short* __restrict__ y,
    const float* __restrict__ Wp, short* __restrict__ wb) {
  if (blockIdx.x >= 256) {
    const int cid = (blockIdx.x - 256) * 2 + blockIdx.y;  // 0..127
    const int i = (cid * 256 + (int)threadIdx.x) * 8;
    const float4 v0 = *(const float4*)&Wp[i];
    const float4 v1 = *(const float4*)&Wp[i + 4];
    short r[8];
    r[0] = f2bf(v0.x); r[1] = f2bf(v0.y); r[2] = f2bf(v0.z); r[3] = f2bf(v0.w);
    r[4] = f2bf(v1.x); r[5] = f2bf(v1.y); r[6] = f2bf(v1.z); r[7] = f2bf(v1.w);
    *(short4*)&wb[i] = *(short4*)&r[0];
    *(short4*)&wb[i + 4] = *(short4*)&r[4];
    return;
  }

  const int seq = blockIdx.x;  // 0..255 = b*64 + w
  const int d = blockIdx.y * 256 + threadIdx.x;
  const int b = seq >> 6;
  const int r = seq & 63;

  size_t base = ((size_t)b * HH * WW + r) * DD + d;
  const size_t step = (size_t)WW * DD;

  float a[NS], bm[NS], cm[NS], s[NS];
#pragma unroll
  for (int i = 0; i < NS; i += 4) {
    float4 t;
    t = *(const float4*)&A[(size_t)d * NS + i];
    a[i] = t.x; a[i + 1] = t.y; a[i + 2] = t.z; a[i + 3] = t.w;
    t = *(const float4*)&Bm[(size_t)d * NS + i];
    bm[i] = t.x; bm[i + 1] = t.y; bm[i + 2] = t.z; bm[i + 3] = t.w;
    t = *(const float4*)&Cm[(size_t)d * NS + i];
    cm[i] = t.x; cm[i + 1] = t.y; cm[i + 2] = t.z; cm[i + 3] = t.w;
  }
  const float dk = Dsk[d];
#pragma unroll
  for (int i = 0; i < NS; ++i) s[i] = 0.f;

  // 2-chunk-ahead prefetch (4-slot ring, unroll 4 keeps indices static)
  float xs[4][8];
#pragma unroll
  for (int i = 0; i < 8; ++i) xs[0][i] = x[base + (size_t)i * step];
#pragma unroll
  for (int i = 0; i < 8; ++i) xs[1][i] = x[base + (size_t)(8 + i) * step];

#pragma unroll 4
  for (int c = 0; c < 8; ++c) {
    const int cur = c & 3;
    if (c < 6) {
      const size_t pbase = base + 16 * step;
#pragma unroll
      for (int i = 0; i < 8; ++i)
        xs[(c + 2) & 3][i] = x[pbase + (size_t)i * step];
    }
#pragma unroll
    for (int i = 0; i < 8; ++i)
      y[base + (size_t)i * step] = f2bf(ssm_step(xs[cur][i], s, a, bm, cm, dk));
    base += 8 * step;
  }
}

// ------- kernel 2: N-split fused scan_v + y_h add + GEMM + bias ------------
// grid 512 = (bh = bx&255, half = bx>>8); blocks bh and bh+256 share an XCD
// under round-robin dispatch, so the duplicated scan reads hit the same L2.
// LDS = Ys only (64 KB) -> 2 blocks/CU, 4 waves/SIMD. Both halves run the
// identical v-scan (cheap VALU); each computes 256 of the 512 out columns.
// B-fragments stream from L2 (Wp bf16 = 512 KB, L2-resident), register-
// prefetched one K-step ahead. B is read once per block (256 KB).
__global__ __launch_bounds__(512, 4) void scanv_gemm_kernel(
    const float* __restrict__ x, const float* __restrict__ A,
    const float* __restrict__ Bm, const float* __restrict__ Cm,
    const float* __restrict__ Dsk, const short* __restrict__ yh,
    const short* __restrict__ Wb, const float* __restrict__ bias,
    float* __restrict__ out) {
  __shared__ __align__(16) short Ys[64 * DD];  // 64 KB [w][d^((w&7)<<3)]

  const int tid = (int)threadIdx.x;  // 0..511
  const int lane = tid & 63;
  const int wid = tid >> 6;               // 0..7
  const int bh = (int)blockIdx.x & 255;   // (b,h)
  const int half = (int)blockIdx.x >> 8;  // 0,1 -> n-half
  const int m0 = bh * 64;
  const int d = tid;

  float a[NS], bm[NS], cm[NS], s[NS];
#pragma unroll
  for (int i = 0; i < NS; i += 4) {
    float4 t;
    t = *(const float4*)&A[(size_t)d * NS + i];
    a[i] = t.x; a[i + 1] = t.y; a[i + 2] = t.z; a[i + 3] = t.w;
    t = *(const float4*)&Bm[(size_t)d * NS + i];
    bm[i] = t.x; bm[i + 1] = t.y; bm[i + 2] = t.z; bm[i + 3] = t.w;
    t = *(const float4*)&Cm[(size_t)d * NS + i];
    cm[i] = t.x; cm[i + 1] = t.y; cm[i + 2] = t.z; cm[i + 3] = t.w;
  }
  const float dk = Dsk[d];
#pragma unroll
  for (int i = 0; i < NS; ++i) s[i] = 0.f;

  size_t base = (size_t)m0 * DD + d;

  // 1-ahead prefetch (2-slot ring) — keeps VGPRs under the (512,4) cap
  float xs[2][8], yp[2][8];
#pragma unroll
  for (int i = 0; i < 8; ++i) xs[0][i] = x[base + (size_t)i * DD];
#pragma unroll
  for (int i = 0; i < 8; ++i) yp[0][i] = bf2f(yh[base + (size_t)i * DD]);

#pragma unroll 2
  for (int c = 0; c < 8; ++c) {
    const int cur = c & 1, nxt = cur ^ 1;
    const size_t nbase = base + 8 * DD;
    if (c < 7) {
#pragma unroll
      for (int i = 0; i < 8; ++i) xs[nxt][i] = x[nbase + (size_t)i * DD];
#pragma unroll
      for (int i = 0; i < 8; ++i) yp[nxt][i] = bf2f(yh[nbase + (size_t)i * DD]);
    }
#pragma unroll
    for (int i = 0; i < 8; ++i) {
      const int w = c * 8 + i;
      const float acc = ssm_step(xs[cur][i], s, a, bm, cm, dk) + yp[cur][i];
      Ys[w * DD + (d ^ ((w & 7) << 3))] = f2bf(acc);
    }
    base = nbase;
  }

  __syncthreads();  // Ys complete (only barrier in the kernel)

  // ---- GEMM: out[m0..+63][nc0..nc0+31 per wave] = Ys @ Wb^T + bias ----
  const int fr = lane & 15;
  const int kfr = (lane >> 4) * 8;        // 0,8,16,24
  const int nc0 = half * 256 + wid * 32;  // this wave's 32 out columns

  f32x4 acc4[4][2];
#pragma unroll
  for (int m = 0; m < 4; ++m)
#pragma unroll
    for (int n = 0; n < 2; ++n) acc4[m][n] = (f32x4){0.f, 0.f, 0.f, 0.f};

  const size_t brow0 = (size_t)(nc0 + fr) * DD;
  const size_t brow1 = (size_t)(nc0 + 16 + fr) * DD;

  // register prefetch of the B fragments, one K-step ahead
  bf16x8 b0 = *(const bf16x8*)(const void*)&Wb[brow0 + kfr];
  bf16x8 b1 = *(const bf16x8*)(const void*)&Wb[brow1 + kfr];

  for (int ks = 0; ks < 16; ++ks) {  // K-steps of 32
    bf16x8 nb0, nb1;
    if (ks < 15) {
      const int kgn = (ks + 1) * 32 + kfr;
      nb0 = *(const bf16x8*)(const void*)&Wb[brow0 + kgn];
      nb1 = *(const bf16x8*)(const void*)&Wb[brow1 + kgn];
    }
    const int kg = ks * 32 + kfr;
    bf16x8 af[4];
#pragma unroll
    for (int m = 0; m < 4; ++m) {
      const int r = m * 16 + fr;  // Y row 0..63
      af[m] = *(const bf16x8*)(const void*)&Ys[r * DD + (kg ^ ((r & 7) << 3))];
    }
#pragma unroll
    for (int m = 0; m < 4; ++m) {
      acc4[m][0] =
          __builtin_amdgcn_mfma_f32_16x16x32_bf16(af[m], b0, acc4[m][0], 0, 0, 0);
      acc4[m][1] =
          __builtin_amdgcn_mfma_f32_16x16x32_bf16(af[m], b1, acc4[m][1], 0, 0, 0);
    }
    if (ks < 15) { b0 = nb0; b1 = nb1; }
  }

  // epilogue: D layout col=lane&15, row=(lane>>4)*4+j  [m89 verified]
  const int c16 = lane & 15;
  const int r4 = (lane >> 4) * 4;
  float bv[2];
#pragma unroll
  for (int n = 0; n < 2; ++n) bv[n] = bias[nc0 + n * 16 + c16];
#pragma unroll
  for (int m = 0; m < 4; ++m) {
    const int rowb = m0 + m * 16 + r4;
#pragma unroll
    for (int n = 0; n < 2; ++n) {
      const int col = nc0 + n * 16 + c16;
#pragma unroll
      for (int j = 0; j < 4; ++j)
        out[(size_t)(rowb + j) * DD + col] = acc4[m][n][j] + bv[n];
    }
  }
}

// ---------------- launcher ----------------
extern "C" void kernel_launch(void* const* d_in, const int* in_sizes, int n_in,
                              void* d_out, int out_size, void* d_ws,
                              size_t ws_size, hipStream_t stream) {
  const float* x = (const float*)d_in[0];
  const float* A = (const float*)d_in[3];
  const float* Bm = (const float*)d_in[4];
  const float* Cm = (const float*)d_in[5];
  const float* Dsk = (const float*)d_in[6];
  const float* Wp = (const float*)d_in[7];
  const float* bpj = (const float*)d_in[8];
  float* out = (float*)d_out;

  short* yh = (short*)d_ws;                                    // 16 MB bf16 y_h
  short* wb = (short*)((char*)d_ws + (size_t)MROWS * DD * 2);  // 512 KB bf16 Wp

  const dim3 grid_h(256 + 64, DD / 256);
  scan_h_kernel<<<grid_h, 256, 0, stream>>>(x, A, Bm, Cm, Dsk, yh, Wp, wb);

  // N-split: 512 blocks (bh, half), 2 blocks/CU @ 64KB LDS
  scanv_gemm_kernel<<<2 * BB * HH, 512, 0, stream>>>(x, A, Bm, Cm, Dsk, yh, wb,
                                                     bpj, out);
}

// Round 11
// 42.326 us; speedup vs baseline: 2.0291x; 1.2429x over previous
//
#include <hip/hip_runtime.h>

// DirectionalScan: B=4, H=64, W=64, D=512, N=8
// out = ((scan_h(x) + scan_v(x)) @ Wp^T) + b_proj
#define BB 4
#define HH 64
#define WW 64
#define DD 512
#define NS 8
#define MROWS (BB * HH * WW)  // 16384

typedef __attribute__((ext_vector_type(8))) __bf16 bf16x8;
typedef __attribute__((ext_vector_type(4))) float f32x4;

__device__ inline short f2bf(float f) {  // RNE f32 -> bf16 bits
  unsigned u = __float_as_uint(f);
  return (short)((u + 0x7fff + ((u >> 16) & 1)) >> 16);
}
__device__ inline float bf2f(short s) {
  return __uint_as_float(((unsigned)(unsigned short)s) << 16);
}

// one SSM step: update states s[], return C.s + D*x via 3-level tree
__device__ inline float ssm_step(float xv, float* s, const float* a,
                                 const float* bm, const float* cm, float dk) {
#pragma unroll
  for (int n = 0; n < NS; ++n) s[n] = fmaf(a[n], s[n], bm[n] * xv);
  float p0 = s[0] * cm[0], p1 = s[1] * cm[1], p2 = s[2] * cm[2],
        p3 = s[3] * cm[3], p4 = s[4] * cm[4], p5 = s[5] * cm[5],
        p6 = s[6] * cm[6], p7 = s[7] * cm[7];
  float q0 = p0 + p1, q1 = p2 + p3, q2 = p4 + p5, q3 = p6 + p7;
  return fmaf(dk, xv, (q0 + q1) + (q2 + q3));
}

// ---------------- kernel 1: scan_h (writes y_h bf16) + fused Wp->bf16 -------
__global__ __launch_bounds__(256) void scan_h_kernel(
    const float* __restrict__ x, const float* __restrict__ A,
    const float* __restrict__ Bm, const float* __restrict__ Cm,
    const float* __restrict__ Dsk, short* __restrict__ y,
    const float* __restrict__ Wp, short* __restrict__ wb) {
  if (blockIdx.x >= 256) {
    const int cid = (blockIdx.x - 256) * 2 + blockIdx.y;  // 0..127
    const int i = (cid * 256 + (int)threadIdx.x) * 8;
    const float4 v0 = *(const float4*)&Wp[i];
    const float4 v1 = *(const float4*)&Wp[i + 4];
    short r[8];
    r[0] = f2bf(v0.x); r[1] = f2bf(v0.y); r[2] = f2bf(v0.z); r[3] = f2bf(v0.w);
    r[4] = f2bf(v1.x); r[5] = f2bf(v1.y); r[6] = f2bf(v1.z); r[7] = f2bf(v1.w);
    *(short4*)&wb[i] = *(short4*)&r[0];
    *(short4*)&wb[i + 4] = *(short4*)&r[4];
    return;
  }

  const int seq = blockIdx.x;  // 0..255 = b*64 + w
  const int d = blockIdx.y * 256 + threadIdx.x;
  const int b = seq >> 6;
  const int r = seq & 63;

  size_t base = ((size_t)b * HH * WW + r) * DD + d;
  const size_t step = (size_t)WW * DD;

  float a[NS], bm[NS], cm[NS], s[NS];
#pragma unroll
  for (int i = 0; i < NS; i += 4) {
    float4 t;
    t = *(const float4*)&A[(size_t)d * NS + i];
    a[i] = t.x; a[i + 1] = t.y; a[i + 2] = t.z; a[i + 3] = t.w;
    t = *(const float4*)&Bm[(size_t)d * NS + i];
    bm[i] = t.x; bm[i + 1] = t.y; bm[i + 2] = t.z; bm[i + 3] = t.w;
    t = *(const float4*)&Cm[(size_t)d * NS + i];
    cm[i] = t.x; cm[i + 1] = t.y; cm[i + 2] = t.z; cm[i + 3] = t.w;
  }
  const float dk = Dsk[d];
#pragma unroll
  for (int i = 0; i < NS; ++i) s[i] = 0.f;

  // 2-chunk-ahead prefetch (4-slot ring, unroll 4 keeps indices static)
  float xs[4][8];
#pragma unroll
  for (int i = 0; i < 8; ++i) xs[0][i] = x[base + (size_t)i * step];
#pragma unroll
  for (int i = 0; i < 8; ++i) xs[1][i] = x[base + (size_t)(8 + i) * step];

#pragma unroll 4
  for (int c = 0; c < 8; ++c) {
    const int cur = c & 3;
    if (c < 6) {
      const size_t pbase = base + 16 * step;
#pragma unroll
      for (int i = 0; i < 8; ++i)
        xs[(c + 2) & 3][i] = x[pbase + (size_t)i * step];
    }
#pragma unroll
    for (int i = 0; i < 8; ++i)
      y[base + (size_t)i * step] = f2bf(ssm_step(xs[cur][i], s, a, bm, cm, dk));
    base += 8 * step;
  }
}

// ------- kernel 2: fused scan_v + y_h add + GEMM + bias (R6 + epilogue) ----
// One block per (b,h) = 64 contiguous output rows; 512 threads = 8 waves.
// Phase 1: thread d scans w, adds y_h, writes bf16 Y-tile to swizzled LDS.
// Phase 2: 64x512x512 GEMM, wave-private Bs staging, counted vmcnt,
// barrier-free K-loop, setprio around MFMA cluster.
// Epilogue: Ys+Bs (dead after K-loop) reused as per-wave 16KB transpose
// buffers so global stores are 256B-contiguous float4 (was 64B segments).
__global__ __launch_bounds__(512) void scanv_gemm_kernel(
    const float* __restrict__ x, const float* __restrict__ A,
    const float* __restrict__ Bm, const float* __restrict__ Cm,
    const float* __restrict__ Dsk, const short* __restrict__ yh,
    const short* __restrict__ Wb, const float* __restrict__ bias,
    float* __restrict__ out) {
  __shared__ __align__(16) char LDSBUF[131072];     // 128 KB, carved manually
  short* Ys = (short*)LDSBUF;                       // 64 KB [w][d^((w&7)<<3)]
  short* Bs0 = (short*)(LDSBUF + 65536);            // 32 KB [n][k^((n&3)<<3)]
  short* Bs1 = (short*)(LDSBUF + 98304);            // 32 KB

  const int tid = (int)threadIdx.x;  // 0..511
  const int lane = tid & 63;
  const int wid = tid >> 6;  // 0..7
  const int m0 = blockIdx.x * 64;
  const int d = tid;

  // stage Bs K-slab ks (32 wide). Wave wid writes chunks wid*4..+3 = rows
  // wid*64..wid*64+63 — exactly the rows it later reads (wave-private).
  auto stageB = [&](int ks, short* bsb) {
    const int k0 = ks * 32;
#pragma unroll
    for (int c = 0; c < 4; ++c) {
      const int chunk = wid * 4 + c;           // 0..31, 16 rows each
      const int n = chunk * 16 + (lane >> 2);  // Wp row
      const int kslot = ((lane & 3) ^ (n & 3)) << 3;
      const short* g = &Wb[(size_t)n * DD + k0 + kslot];
      __builtin_amdgcn_global_load_lds(
          (const __attribute__((address_space(1))) unsigned int*)g,
          (__attribute__((address_space(3))) unsigned int*)((char*)bsb +
                                                            chunk * 1024),
          16, 0, 0);
    }
  };

  float a[NS], bm[NS], cm[NS], s[NS];
#pragma unroll
  for (int i = 0; i < NS; i += 4) {
    float4 t;
    t = *(const float4*)&A[(size_t)d * NS + i];
    a[i] = t.x; a[i + 1] = t.y; a[i + 2] = t.z; a[i + 3] = t.w;
    t = *(const float4*)&Bm[(size_t)d * NS + i];
    bm[i] = t.x; bm[i + 1] = t.y; bm[i + 2] = t.z; bm[i + 3] = t.w;
    t = *(const float4*)&Cm[(size_t)d * NS + i];
    cm[i] = t.x; cm[i + 1] = t.y; cm[i + 2] = t.z; cm[i + 3] = t.w;
  }
  const float dk = Dsk[d];
#pragma unroll
  for (int i = 0; i < NS; ++i) s[i] = 0.f;

  size_t base = (size_t)m0 * DD + d;
  stageB(0, Bs0);  // lands under the scan; long done before GEMM

  // 2-chunk-ahead prefetch of x and y_h
  float xs[4][8], yp[4][8];
#pragma unroll
  for (int i = 0; i < 8; ++i) xs[0][i] = x[base + (size_t)i * DD];
#pragma unroll
  for (int i = 0; i < 8; ++i) yp[0][i] = bf2f(yh[base + (size_t)i * DD]);
#pragma unroll
  for (int i = 0; i < 8; ++i) xs[1][i] = x[base + (size_t)(8 + i) * DD];
#pragma unroll
  for (int i = 0; i < 8; ++i) yp[1][i] = bf2f(yh[base + (size_t)(8 + i) * DD]);

#pragma unroll 4
  for (int c = 0; c < 8; ++c) {
    const int cur = c & 3;
    if (c < 6) {
      const size_t pbase = base + 16 * DD;
#pragma unroll
      for (int i = 0; i < 8; ++i)
        xs[(c + 2) & 3][i] = x[pbase + (size_t)i * DD];
#pragma unroll
      for (int i = 0; i < 8; ++i)
        yp[(c + 2) & 3][i] = bf2f(yh[pbase + (size_t)i * DD]);
    }
#pragma unroll
    for (int i = 0; i < 8; ++i) {
      const int w = c * 8 + i;
      const float acc = ssm_step(xs[cur][i], s, a, bm, cm, dk) + yp[cur][i];
      Ys[w * DD + (d ^ ((w & 7) << 3))] = f2bf(acc);
    }
    base += 8 * DD;
  }

  __syncthreads();  // Ys complete

  // ---- GEMM: out[m0..+63][0..511] = Ys @ Wb^T + bias ----
  f32x4 acc4[4][4];
#pragma unroll
  for (int m = 0; m < 4; ++m)
#pragma unroll
    for (int n = 0; n < 4; ++n) acc4[m][n] = (f32x4){0.f, 0.f, 0.f, 0.f};

  const int fr = lane & 15;
  const int kfr = (lane >> 4) * 8;  // 0,8,16,24

  int cur = 0;
  for (int ks = 0; ks < 16; ++ks) {  // K-steps of 32, double-buffered
    if (ks < 15) {
      stageB(ks + 1, (cur ^ 1) ? Bs1 : Bs0);
      asm volatile("s_waitcnt vmcnt(4)" ::: "memory");  // stage(ks) done
    } else {
      asm volatile("s_waitcnt vmcnt(0)" ::: "memory");
    }
    __builtin_amdgcn_sched_barrier(0);  // rule #18: fence ds_reads below wait

    const short* bsr = cur ? Bs1 : Bs0;
    bf16x8 af[4], bfv[4];
    const int kg = ks * 32 + kfr;
#pragma unroll
    for (int m = 0; m < 4; ++m) {
      const int r = m * 16 + fr;  // Y row 0..63
      af[m] = *(const bf16x8*)(const void*)&Ys[r * DD + (kg ^ ((r & 7) << 3))];
    }
#pragma unroll
    for (int n = 0; n < 4; ++n) {
      const int nn = wid * 64 + n * 16 + fr;  // out col (wave-private rows)
      bfv[n] = *(const bf16x8*)(const void*)&bsr[nn * 32 +
                                                 (kfr ^ ((nn & 3) << 3))];
    }
    __builtin_amdgcn_s_setprio(1);
#pragma unroll
    for (int m = 0; m < 4; ++m)
#pragma unroll
      for (int n = 0; n < 4; ++n)
        acc4[m][n] = __builtin_amdgcn_mfma_f32_16x16x32_bf16(
            af[m], bfv[n], acc4[m][n], 0, 0, 0);
    __builtin_amdgcn_s_setprio(0);
    __builtin_amdgcn_sched_barrier(0);  // keep iter body intact (WAR safety)
    cur ^= 1;
  }

  // ---- epilogue: per-wave LDS transpose -> 256B-contiguous stores ----
  __syncthreads();  // all waves done reading Ys/Bs; LDS reusable
  float* Wt = (float*)(LDSBUF + (size_t)wid * 16384);  // 16KB/wave: [64][64]

  const int c16 = lane & 15;
  float bv[4];
#pragma unroll
  for (int n = 0; n < 4; ++n) bv[n] = bias[wid * 64 + n * 16 + c16];

  // write: D layout col=lane&15, row=(lane>>4)*4+j  [m89 verified]
#pragma unroll
  for (int m = 0; m < 4; ++m)
#pragma unroll
    for (int n = 0; n < 4; ++n)
#pragma unroll
      for (int j = 0; j < 4; ++j) {
        const int row = m * 16 + (lane >> 4) * 4 + j;
        const int col = n * 16 + c16;
        Wt[row * 64 + col] = acc4[m][n][j] + bv[n];
      }
  // read row-major + store: each inst = 4 rows x 256B contiguous segments
#pragma unroll
  for (int rr = 0; rr < 16; ++rr) {
    const int row = rr * 4 + (lane >> 4);  // 0..63
    const int col4 = c16 * 4;
    const float4 v = *(const float4*)&Wt[row * 64 + col4];
    *(float4*)&out[(size_t)(m0 + row) * DD + wid * 64 + col4] = v;
  }
}

// ---------------- launcher ----------------
extern "C" void kernel_launch(void* const* d_in, const int* in_sizes, int n_in,
                              void* d_out, int out_size, void* d_ws,
                              size_t ws_size, hipStream_t stream) {
  const float* x = (const float*)d_in[0];
  const float* A = (const float*)d_in[3];
  const float* Bm = (const float*)d_in[4];
  const float* Cm = (const float*)d_in[5];
  const float* Dsk = (const float*)d_in[6];
  const float* Wp = (const float*)d_in[7];
  const float* bpj = (const float*)d_in[8];
  float* out = (float*)d_out;

  short* yh = (short*)d_ws;                                    // 16 MB bf16 y_h
  short* wb = (short*)((char*)d_ws + (size_t)MROWS * DD * 2);  // 512 KB bf16 Wp

  const dim3 grid_h(256 + 64, DD / 256);
  scan_h_kernel<<<grid_h, 256, 0, stream>>>(x, A, Bm, Cm, Dsk, yh, Wp, wb);

  scanv_gemm_kernel<<<BB * HH, 512, 0, stream>>>(x, A, Bm, Cm, Dsk, yh, wb,
                                                 bpj, out);
}